// Round 9
// baseline (265.934 us; speedup 1.0000x reference)
//
#include <hip/hip_runtime.h>
#include <hip/hip_bf16.h>

typedef __hip_bfloat16 bf16;
typedef __attribute__((ext_vector_type(8))) short short8;

static constexpr int NPOS = 65536;  // 64*64*16

__device__ __forceinline__ float bs2f(short s) {
  union { float f; unsigned u; } cv;
  cv.u = ((unsigned)(unsigned short)s) << 16;
  return cv.f;
}
__device__ __forceinline__ short f2bs(float f) {
  bf16 b = __float2bfloat16(f);
  short r;
  __builtin_memcpy(&r, &b, 2);
  return r;
}

// K1a: partial sums + xu materialization (bf16). 2048 blocks:
// 0..1023 -> x channel b>>4, h-slab (b&15)*4; thread = one (h,w), 16 z's.
// 1024..2047 -> skip (float4 reads).
__global__ __launch_bounds__(256) void k_partial(const float* __restrict__ x,
                                                 const float* __restrict__ skip,
                                                 bf16* __restrict__ xu,
                                                 float* __restrict__ partials) {
  __shared__ float s1[256];
  __shared__ float s2[256];
  int b = blockIdx.x, tid = threadIdx.x;
  float sum = 0.f, sq = 0.f;
  if (b < 1024) {
    int c = b >> 4;
    int h = (b & 15) * 4 + (tid >> 6);
    int w = tid & 63;
    float fh = (float)h * (31.0f / 63.0f);
    int ih = (int)fh; if (ih > 30) ih = 30;
    float wh = fh - (float)ih;
    float fw = (float)w * (31.0f / 63.0f);
    int iw = (int)fw; if (iw > 30) iw = 30;
    float ww = fw - (float)iw;
    const float* base = x + c * 8192 + ih * 256 + iw * 8;
    float4 A0 = *(const float4*)(base);       // (ih,   iw,   z0..3)
    float4 A1 = *(const float4*)(base + 4);   // (ih,   iw,   z4..7)
    float4 B0 = *(const float4*)(base + 8);   // (ih,   iw+1)
    float4 B1 = *(const float4*)(base + 12);
    float4 C0 = *(const float4*)(base + 256); // (ih+1, iw)
    float4 C1 = *(const float4*)(base + 260);
    float4 D0 = *(const float4*)(base + 264); // (ih+1, iw+1)
    float4 D1 = *(const float4*)(base + 268);
    float ra[8] = {A0.x, A0.y, A0.z, A0.w, A1.x, A1.y, A1.z, A1.w};
    float rb[8] = {B0.x, B0.y, B0.z, B0.w, B1.x, B1.y, B1.z, B1.w};
    float rc[8] = {C0.x, C0.y, C0.z, C0.w, C1.x, C1.y, C1.z, C1.w};
    float rd[8] = {D0.x, D0.y, D0.z, D0.w, D1.x, D1.y, D1.z, D1.w};
    short8 o0, o1;
#pragma unroll
    for (int z = 0; z < 16; z++) {
      float fz = (float)z * (7.0f / 15.0f);
      int iz = (int)fz; if (iz > 6) iz = 6;   // compile-time after unroll
      float wz = fz - (float)iz;
      float va = ra[iz] * (1.f - wz) + ra[iz + 1] * wz;
      float vb = rb[iz] * (1.f - wz) + rb[iz + 1] * wz;
      float vc = rc[iz] * (1.f - wz) + rc[iz + 1] * wz;
      float vd = rd[iz] * (1.f - wz) + rd[iz + 1] * wz;
      float v0 = va * (1.f - ww) + vb * ww;
      float v1 = vc * (1.f - ww) + vd * ww;
      float v = v0 * (1.f - wh) + v1 * wh;
      sum += v; sq += v * v;
      if (z < 8) o0[z] = f2bs(v); else o1[z - 8] = f2bs(v);
    }
    bf16* xo = xu + (size_t)c * NPOS + h * 1024 + w * 16;
    *(short8*)xo = o0;
    *(short8*)(xo + 8) = o1;
  } else {
    int bb = b - 1024;
    const float4* p =
        (const float4*)(skip + (size_t)(bb >> 4) * NPOS + (bb & 15) * 4096);
    for (int i = tid; i < 1024; i += 256) {
      float4 v = p[i];
      sum += v.x + v.y + v.z + v.w;
      sq += v.x * v.x + v.y * v.y + v.z * v.z + v.w * v.w;
    }
  }
  s1[tid] = sum; s2[tid] = sq;
  __syncthreads();
  for (int s = 128; s > 0; s >>= 1) {
    if (tid < s) { s1[tid] += s1[tid + s]; s2[tid] += s2[tid + s]; }
    __syncthreads();
  }
  if (tid == 0) { partials[2 * b] = s1[0]; partials[2 * b + 1] = s2[0]; }
}

// K1b: finalize. stats: [mean_xu(64), rstd_xu(64), mean_sk(64), rstd_sk(64)]
__global__ __launch_bounds__(128) void k_finalize(const float* __restrict__ partials,
                                                  float* __restrict__ stats) {
  int t = threadIdx.x;
  int base = (t < 64) ? t * 16 : 1024 + (t - 64) * 16;
  float sum = 0.f, sq = 0.f;
#pragma unroll
  for (int j = 0; j < 16; j++) {
    sum += partials[2 * (base + j)];
    sq  += partials[2 * (base + j) + 1];
  }
  float m = sum * (1.0f / NPOS);
  float var = sq * (1.0f / NPOS) - m * m;
  int off = (t < 64) ? 0 : 128;
  int c = t & 63;
  stats[off + c] = m;
  stats[off + 64 + c] = rsqrtf(var + 1e-5f);
}

// K2: norm + K/V/Q projections. Weights via wave-uniform scalar loads.
__global__ __launch_bounds__(256) void k_proj_kvq(
    const bf16* __restrict__ xu, const float* __restrict__ skip,
    const float* __restrict__ stats,
    const float* __restrict__ Wk, const float* __restrict__ bk,
    const float* __restrict__ Wv, const float* __restrict__ bv,
    const float* __restrict__ Wq, const float* __restrict__ bq,
    bf16* __restrict__ kbuf, bf16* __restrict__ vbuf, bf16* __restrict__ qbuf) {
  __shared__ float xt[4096];  // [c][t] 64x64 normalized values
  int tid = threadIdx.x;
  int p0 = blockIdx.x * 64;
  for (int ii = tid; ii < 512; ii += 256) {
    int c = ii >> 3, t0 = (ii & 7) * 8;
    short8 v8 = *(const short8*)(xu + (size_t)c * NPOS + p0 + t0);
    float m = stats[c], r = stats[64 + c];
#pragma unroll
    for (int u = 0; u < 8; u++) xt[c * 64 + t0 + u] = (bs2f(v8[u]) - m) * r;
  }
  __syncthreads();
  int t = tid & 63;
  int j0 = __builtin_amdgcn_readfirstlane((tid >> 6) * 16);  // wave-uniform
  size_t p = (size_t)(p0 + t);
  float a[16];
  short8 s0, s1v;

  // pass 1: K
#pragma unroll
  for (int u = 0; u < 16; u++) a[u] = bk[j0 + u];
  for (int c = 0; c < 64; c++) {
    float xv = xt[c * 64 + t];
    const float* wr = Wk + c * 64 + j0;  // uniform -> s_load
#pragma unroll
    for (int u = 0; u < 16; u++) a[u] += xv * wr[u];
  }
#pragma unroll
  for (int u = 0; u < 8; u++) { s0[u] = f2bs(a[u]); s1v[u] = f2bs(a[8 + u]); }
  *(short8*)(kbuf + p * 64 + j0) = s0;
  *(short8*)(kbuf + p * 64 + j0 + 8) = s1v;

  // pass 2: V
#pragma unroll
  for (int u = 0; u < 16; u++) a[u] = bv[j0 + u];
  for (int c = 0; c < 64; c++) {
    float xv = xt[c * 64 + t];
    const float* wr = Wv + c * 64 + j0;
#pragma unroll
    for (int u = 0; u < 16; u++) a[u] += xv * wr[u];
  }
#pragma unroll
  for (int u = 0; u < 8; u++) { s0[u] = f2bs(a[u]); s1v[u] = f2bs(a[8 + u]); }
  *(short8*)(vbuf + p * 64 + j0) = s0;
  *(short8*)(vbuf + p * 64 + j0 + 8) = s1v;

  __syncthreads();
  for (int ii = tid; ii < 1024; ii += 256) {
    int c = ii >> 4, t0 = (ii & 15) * 4;
    float4 v = *(const float4*)(skip + (size_t)c * NPOS + p0 + t0);
    float m = stats[128 + c], r = stats[192 + c];
    xt[c * 64 + t0]     = (v.x - m) * r;
    xt[c * 64 + t0 + 1] = (v.y - m) * r;
    xt[c * 64 + t0 + 2] = (v.z - m) * r;
    xt[c * 64 + t0 + 3] = (v.w - m) * r;
  }
  __syncthreads();

  // pass 3: Q (pre-scaled by 8^-0.5)
  const float scale = 0.35355339059327373f;
#pragma unroll
  for (int u = 0; u < 16; u++) a[u] = bq[j0 + u];
  for (int c = 0; c < 64; c++) {
    float xv = xt[c * 64 + t];
    const float* wr = Wq + c * 64 + j0;
#pragma unroll
    for (int u = 0; u < 16; u++) a[u] += xv * wr[u];
  }
#pragma unroll
  for (int u = 0; u < 8; u++) {
    s0[u] = f2bs(a[u] * scale); s1v[u] = f2bs(a[8 + u] * scale);
  }
  *(short8*)(qbuf + p * 64 + j0) = s0;
  *(short8*)(qbuf + p * 64 + j0 + 8) = s1v;
}

// K3: 27-neighbor attention, flat softmax (27 independent logits, one max,
// one fused exp+V pass — all offsets compile-time constants off one clamped
// base). 512 threads = 64 positions x 8 heads. XCD-contiguous swizzle.
__global__ __launch_bounds__(512, 4) void k_attn(
    const bf16* __restrict__ qbuf, const bf16* __restrict__ kbuf,
    const bf16* __restrict__ vbuf,
    const float* __restrict__ Wo, const float* __restrict__ bo,
    const float* __restrict__ rpb, float* __restrict__ out) {
  __shared__ float rp[1000];
  __shared__ float oT[64 * 65];  // [pos][j], stride 65
  int tid = threadIdx.x;
  int b = blockIdx.x;
  int sb = ((b & 7) << 7) + (b >> 3);  // XCD-contiguous spatial swizzle
  int p0 = sb * 64;
  for (int i = tid; i < 1000; i += 512) rp[i] = rpb[i];
  __syncthreads();

  int head = tid & 7, pp = tid >> 3;
  int p = p0 + pp;
  int h = p >> 10, w = (p >> 4) & 63, z = p & 15;

  short8 q8 = *(const short8*)(qbuf + (size_t)p * 64 + head * 8);
  float q[8];
#pragma unroll
  for (int d = 0; d < 8; d++) q[d] = bs2f(q8[d]);

  int sh = h - 1; if (sh < 0) sh = 0; if (sh > 61) sh = 61;
  int sw = w - 1; if (sw < 0) sw = 0; if (sw > 61) sw = 61;
  int sz = z - 1; if (sz < 0) sz = 0; if (sz > 13) sz = 13;

  // one clamped base; every neighbor is base + compile-time constant
  const bf16* kb = kbuf + (size_t)(sh * 1024 + sw * 16 + sz) * 64 + head * 8;
  const bf16* vb = vbuf + (size_t)(sh * 1024 + sw * 16 + sz) * 64 + head * 8;
  int rbase = ((sh - h + 2) * 5 + (sw - w + 2)) * 5 + (sz - z + 2) + head * 125;

  float s[27];
#pragma unroll
  for (int j = 0; j < 27; j++) {
    int kh = j / 9, kw = (j / 9 == 0 ? j : j % 9) / 3, kz = j % 3;  // constants
    kw = (j % 9) / 3;
    int coff = (kh * 1024 + kw * 16 + kz) * 64;  // element offset, constant
    short8 k8 = *(const short8*)(kb + coff);
    float sv = q[0] * bs2f(k8[0]) + q[1] * bs2f(k8[1]) +
               q[2] * bs2f(k8[2]) + q[3] * bs2f(k8[3]) +
               q[4] * bs2f(k8[4]) + q[5] * bs2f(k8[5]) +
               q[6] * bs2f(k8[6]) + q[7] * bs2f(k8[7]);
    s[j] = sv + rp[rbase + (kh * 5 + kw) * 5 + kz];
  }
  // max: 13 pairs + tail, shallow chain
  float M = s[26];
#pragma unroll
  for (int j = 0; j < 13; j++) M = fmaxf(M, fmaxf(s[2 * j], s[2 * j + 1]));

  float lrun = 0.f;
  float oa[8];
#pragma unroll
  for (int d = 0; d < 8; d++) oa[d] = 0.f;
#pragma unroll
  for (int j = 0; j < 27; j++) {
    int kh = j / 9, kw = (j % 9) / 3, kz = j % 3;
    int coff = (kh * 1024 + kw * 16 + kz) * 64;
    short8 v8 = *(const short8*)(vb + coff);
    float pw = __expf(s[j] - M);
    lrun += pw;
#pragma unroll
    for (int d = 0; d < 8; d++) oa[d] += pw * bs2f(v8[d]);
  }
  float inv = 1.0f / lrun;
#pragma unroll
  for (int d = 0; d < 8; d++) oT[pp * 65 + head * 8 + d] = oa[d] * inv;
  __syncthreads();

  // output projection: wave wid -> channels wid*8..wid*8+7, lane l = position
  int wid = __builtin_amdgcn_readfirstlane(tid >> 6);
  int l = tid & 63;
  float acc[8];
#pragma unroll
  for (int u = 0; u < 8; u++) acc[u] = bo[wid * 8 + u];
  for (int j = 0; j < 64; j++) {
    float ov = oT[l * 65 + j];
    const float* wr = Wo + j * 64 + wid * 8;  // uniform -> s_load
#pragma unroll
    for (int u = 0; u < 8; u++) acc[u] += ov * wr[u];
  }
#pragma unroll
  for (int u = 0; u < 8; u++)
    out[(size_t)(wid * 8 + u) * NPOS + p0 + l] = acc[u];
}

extern "C" void kernel_launch(void* const* d_in, const int* in_sizes, int n_in,
                              void* d_out, int out_size, void* d_ws, size_t ws_size,
                              hipStream_t stream) {
  const float* x    = (const float*)d_in[0];
  const float* skip = (const float*)d_in[1];
  const float* Wq   = (const float*)d_in[2];
  const float* bq   = (const float*)d_in[3];
  const float* Wk   = (const float*)d_in[4];
  const float* bk   = (const float*)d_in[5];
  const float* Wv   = (const float*)d_in[6];
  const float* bv   = (const float*)d_in[7];
  const float* Wo   = (const float*)d_in[8];
  const float* bo   = (const float*)d_in[9];
  const float* rpb  = (const float*)d_in[10];

  // ws layout (32 MB + ~18 KB):
  bf16* xu        = (bf16*)d_ws;                                 // 8 MB
  bf16* kbuf      = (bf16*)((char*)d_ws + ((size_t)8 << 20));    // 8 MB
  bf16* vbuf      = (bf16*)((char*)d_ws + ((size_t)16 << 20));   // 8 MB
  bf16* qbuf      = (bf16*)((char*)d_ws + ((size_t)24 << 20));   // 8 MB
  float* stats    = (float*)((char*)d_ws + ((size_t)32 << 20));  // 256 fp32
  float* partials = stats + 256;                                 // 4096 fp32
  float* out = (float*)d_out;

  hipLaunchKernelGGL(k_partial, dim3(2048), dim3(256), 0, stream, x, skip, xu,
                     partials);
  hipLaunchKernelGGL(k_finalize, dim3(1), dim3(128), 0, stream, partials, stats);
  hipLaunchKernelGGL(k_proj_kvq, dim3(1024), dim3(256), 0, stream, xu, skip,
                     stats, Wk, bk, Wv, bv, Wq, bq, kbuf, vbuf, qbuf);
  hipLaunchKernelGGL(k_attn, dim3(1024), dim3(512), 0, stream, qbuf, kbuf, vbuf,
                     Wo, bo, rpb, out);
}

// Round 10
// 159.653 us; speedup vs baseline: 1.6657x; 1.6657x over previous
//
#include <hip/hip_runtime.h>
#include <hip/hip_bf16.h>

typedef __hip_bfloat16 bf16;
typedef __attribute__((ext_vector_type(8))) short short8;

static constexpr int NPOS = 65536;  // 64*64*16

__device__ __forceinline__ float bs2f(short s) {
  union { float f; unsigned u; } cv;
  cv.u = ((unsigned)(unsigned short)s) << 16;
  return cv.f;
}
__device__ __forceinline__ short f2bs(float f) {
  bf16 b = __float2bfloat16(f);
  short r;
  __builtin_memcpy(&r, &b, 2);
  return r;
}

// K1a: partial sums + xu materialization (bf16). 2048 blocks:
// 0..1023 -> x channel b>>4, h-slab (b&15)*4; thread = one (h,w), 16 z's.
// 1024..2047 -> skip (float4 reads).
__global__ __launch_bounds__(256) void k_partial(const float* __restrict__ x,
                                                 const float* __restrict__ skip,
                                                 bf16* __restrict__ xu,
                                                 float* __restrict__ partials) {
  __shared__ float s1[256];
  __shared__ float s2[256];
  int b = blockIdx.x, tid = threadIdx.x;
  float sum = 0.f, sq = 0.f;
  if (b < 1024) {
    int c = b >> 4;
    int h = (b & 15) * 4 + (tid >> 6);
    int w = tid & 63;
    float fh = (float)h * (31.0f / 63.0f);
    int ih = (int)fh; if (ih > 30) ih = 30;
    float wh = fh - (float)ih;
    float fw = (float)w * (31.0f / 63.0f);
    int iw = (int)fw; if (iw > 30) iw = 30;
    float ww = fw - (float)iw;
    const float* base = x + c * 8192 + ih * 256 + iw * 8;
    float4 A0 = *(const float4*)(base);       // (ih,   iw,   z0..3)
    float4 A1 = *(const float4*)(base + 4);   // (ih,   iw,   z4..7)
    float4 B0 = *(const float4*)(base + 8);   // (ih,   iw+1)
    float4 B1 = *(const float4*)(base + 12);
    float4 C0 = *(const float4*)(base + 256); // (ih+1, iw)
    float4 C1 = *(const float4*)(base + 260);
    float4 D0 = *(const float4*)(base + 264); // (ih+1, iw+1)
    float4 D1 = *(const float4*)(base + 268);
    float ra[8] = {A0.x, A0.y, A0.z, A0.w, A1.x, A1.y, A1.z, A1.w};
    float rb[8] = {B0.x, B0.y, B0.z, B0.w, B1.x, B1.y, B1.z, B1.w};
    float rc[8] = {C0.x, C0.y, C0.z, C0.w, C1.x, C1.y, C1.z, C1.w};
    float rd[8] = {D0.x, D0.y, D0.z, D0.w, D1.x, D1.y, D1.z, D1.w};
    short8 o0, o1;
#pragma unroll
    for (int z = 0; z < 16; z++) {
      float fz = (float)z * (7.0f / 15.0f);
      int iz = (int)fz; if (iz > 6) iz = 6;   // compile-time after unroll
      float wz = fz - (float)iz;
      float va = ra[iz] * (1.f - wz) + ra[iz + 1] * wz;
      float vb = rb[iz] * (1.f - wz) + rb[iz + 1] * wz;
      float vc = rc[iz] * (1.f - wz) + rc[iz + 1] * wz;
      float vd = rd[iz] * (1.f - wz) + rd[iz + 1] * wz;
      float v0 = va * (1.f - ww) + vb * ww;
      float v1 = vc * (1.f - ww) + vd * ww;
      float v = v0 * (1.f - wh) + v1 * wh;
      sum += v; sq += v * v;
      if (z < 8) o0[z] = f2bs(v); else o1[z - 8] = f2bs(v);
    }
    bf16* xo = xu + (size_t)c * NPOS + h * 1024 + w * 16;
    *(short8*)xo = o0;
    *(short8*)(xo + 8) = o1;
  } else {
    int bb = b - 1024;
    const float4* p =
        (const float4*)(skip + (size_t)(bb >> 4) * NPOS + (bb & 15) * 4096);
    for (int i = tid; i < 1024; i += 256) {
      float4 v = p[i];
      sum += v.x + v.y + v.z + v.w;
      sq += v.x * v.x + v.y * v.y + v.z * v.z + v.w * v.w;
    }
  }
  s1[tid] = sum; s2[tid] = sq;
  __syncthreads();
  for (int s = 128; s > 0; s >>= 1) {
    if (tid < s) { s1[tid] += s1[tid + s]; s2[tid] += s2[tid + s]; }
    __syncthreads();
  }
  if (tid == 0) { partials[2 * b] = s1[0]; partials[2 * b + 1] = s2[0]; }
}

// K1b: finalize. stats: [mean_xu(64), rstd_xu(64), mean_sk(64), rstd_sk(64)]
__global__ __launch_bounds__(128) void k_finalize(const float* __restrict__ partials,
                                                  float* __restrict__ stats) {
  int t = threadIdx.x;
  int base = (t < 64) ? t * 16 : 1024 + (t - 64) * 16;
  float sum = 0.f, sq = 0.f;
#pragma unroll
  for (int j = 0; j < 16; j++) {
    sum += partials[2 * (base + j)];
    sq  += partials[2 * (base + j) + 1];
  }
  float m = sum * (1.0f / NPOS);
  float var = sq * (1.0f / NPOS) - m * m;
  int off = (t < 64) ? 0 : 128;
  int c = t & 63;
  stats[off + c] = m;
  stats[off + 64 + c] = rsqrtf(var + 1e-5f);
}

// K2: norm + K/V/Q projections. Weights via wave-uniform scalar loads.
__global__ __launch_bounds__(256) void k_proj_kvq(
    const bf16* __restrict__ xu, const float* __restrict__ skip,
    const float* __restrict__ stats,
    const float* __restrict__ Wk, const float* __restrict__ bk,
    const float* __restrict__ Wv, const float* __restrict__ bv,
    const float* __restrict__ Wq, const float* __restrict__ bq,
    bf16* __restrict__ kbuf, bf16* __restrict__ vbuf, bf16* __restrict__ qbuf) {
  __shared__ float xt[4096];  // [c][t] 64x64 normalized values
  int tid = threadIdx.x;
  int p0 = blockIdx.x * 64;
  for (int ii = tid; ii < 512; ii += 256) {
    int c = ii >> 3, t0 = (ii & 7) * 8;
    short8 v8 = *(const short8*)(xu + (size_t)c * NPOS + p0 + t0);
    float m = stats[c], r = stats[64 + c];
#pragma unroll
    for (int u = 0; u < 8; u++) xt[c * 64 + t0 + u] = (bs2f(v8[u]) - m) * r;
  }
  __syncthreads();
  int t = tid & 63;
  int j0 = __builtin_amdgcn_readfirstlane((tid >> 6) * 16);  // wave-uniform
  size_t p = (size_t)(p0 + t);
  float a[16];
  short8 s0, s1v;

  // pass 1: K
#pragma unroll
  for (int u = 0; u < 16; u++) a[u] = bk[j0 + u];
  for (int c = 0; c < 64; c++) {
    float xv = xt[c * 64 + t];
    const float* wr = Wk + c * 64 + j0;  // uniform -> s_load
#pragma unroll
    for (int u = 0; u < 16; u++) a[u] += xv * wr[u];
  }
#pragma unroll
  for (int u = 0; u < 8; u++) { s0[u] = f2bs(a[u]); s1v[u] = f2bs(a[8 + u]); }
  *(short8*)(kbuf + p * 64 + j0) = s0;
  *(short8*)(kbuf + p * 64 + j0 + 8) = s1v;

  // pass 2: V
#pragma unroll
  for (int u = 0; u < 16; u++) a[u] = bv[j0 + u];
  for (int c = 0; c < 64; c++) {
    float xv = xt[c * 64 + t];
    const float* wr = Wv + c * 64 + j0;
#pragma unroll
    for (int u = 0; u < 16; u++) a[u] += xv * wr[u];
  }
#pragma unroll
  for (int u = 0; u < 8; u++) { s0[u] = f2bs(a[u]); s1v[u] = f2bs(a[8 + u]); }
  *(short8*)(vbuf + p * 64 + j0) = s0;
  *(short8*)(vbuf + p * 64 + j0 + 8) = s1v;

  __syncthreads();
  for (int ii = tid; ii < 1024; ii += 256) {
    int c = ii >> 4, t0 = (ii & 15) * 4;
    float4 v = *(const float4*)(skip + (size_t)c * NPOS + p0 + t0);
    float m = stats[128 + c], r = stats[192 + c];
    xt[c * 64 + t0]     = (v.x - m) * r;
    xt[c * 64 + t0 + 1] = (v.y - m) * r;
    xt[c * 64 + t0 + 2] = (v.z - m) * r;
    xt[c * 64 + t0 + 3] = (v.w - m) * r;
  }
  __syncthreads();

  // pass 3: Q (pre-scaled by 8^-0.5)
  const float scale = 0.35355339059327373f;
#pragma unroll
  for (int u = 0; u < 16; u++) a[u] = bq[j0 + u];
  for (int c = 0; c < 64; c++) {
    float xv = xt[c * 64 + t];
    const float* wr = Wq + c * 64 + j0;
#pragma unroll
    for (int u = 0; u < 16; u++) a[u] += xv * wr[u];
  }
#pragma unroll
  for (int u = 0; u < 8; u++) {
    s0[u] = f2bs(a[u] * scale); s1v[u] = f2bs(a[8 + u] * scale);
  }
  *(short8*)(qbuf + p * 64 + j0) = s0;
  *(short8*)(qbuf + p * 64 + j0 + 8) = s1v;
}

// K3: 27-neighbor attention, flat softmax. 512 threads = 64 positions x 8
// heads. __launch_bounds__(512,2): 128-VGPR budget — s[27]+q[8]+oa[8] must
// live in registers (R9's (512,4) capped VGPRs at 64 and spilled 336 MB).
__global__ __launch_bounds__(512, 2) void k_attn(
    const bf16* __restrict__ qbuf, const bf16* __restrict__ kbuf,
    const bf16* __restrict__ vbuf,
    const float* __restrict__ Wo, const float* __restrict__ bo,
    const float* __restrict__ rpb, float* __restrict__ out) {
  __shared__ float rp[1000];
  __shared__ float oT[64 * 65];  // [pos][j], stride 65
  int tid = threadIdx.x;
  int b = blockIdx.x;
  int sb = ((b & 7) << 7) + (b >> 3);  // XCD-contiguous spatial swizzle
  int p0 = sb * 64;
  for (int i = tid; i < 1000; i += 512) rp[i] = rpb[i];
  __syncthreads();

  int head = tid & 7, pp = tid >> 3;
  int p = p0 + pp;
  int h = p >> 10, w = (p >> 4) & 63, z = p & 15;

  short8 q8 = *(const short8*)(qbuf + (size_t)p * 64 + head * 8);
  float q[8];
#pragma unroll
  for (int d = 0; d < 8; d++) q[d] = bs2f(q8[d]);

  int sh = h - 1; if (sh < 0) sh = 0; if (sh > 61) sh = 61;
  int sw = w - 1; if (sw < 0) sw = 0; if (sw > 61) sw = 61;
  int sz = z - 1; if (sz < 0) sz = 0; if (sz > 13) sz = 13;

  // one clamped base; every neighbor is base + compile-time constant
  const bf16* kb = kbuf + (size_t)(sh * 1024 + sw * 16 + sz) * 64 + head * 8;
  const bf16* vb = vbuf + (size_t)(sh * 1024 + sw * 16 + sz) * 64 + head * 8;
  int rbase = ((sh - h + 2) * 5 + (sw - w + 2)) * 5 + (sz - z + 2) + head * 125;

  float s[27];
#pragma unroll
  for (int j = 0; j < 27; j++) {
    int kh = j / 9, kw = (j % 9) / 3, kz = j % 3;      // compile-time
    int coff = (kh * 1024 + kw * 16 + kz) * 64;         // constant offset
    short8 k8 = *(const short8*)(kb + coff);
    float sv = q[0] * bs2f(k8[0]) + q[1] * bs2f(k8[1]) +
               q[2] * bs2f(k8[2]) + q[3] * bs2f(k8[3]) +
               q[4] * bs2f(k8[4]) + q[5] * bs2f(k8[5]) +
               q[6] * bs2f(k8[6]) + q[7] * bs2f(k8[7]);
    s[j] = sv + rp[rbase + (kh * 5 + kw) * 5 + kz];
  }
  // max: shallow tree
  float M = s[26];
#pragma unroll
  for (int j = 0; j < 13; j++) M = fmaxf(M, fmaxf(s[2 * j], s[2 * j + 1]));

  float lrun = 0.f;
  float oa[8];
#pragma unroll
  for (int d = 0; d < 8; d++) oa[d] = 0.f;
#pragma unroll
  for (int j = 0; j < 27; j++) {
    int kh = j / 9, kw = (j % 9) / 3, kz = j % 3;
    int coff = (kh * 1024 + kw * 16 + kz) * 64;
    short8 v8 = *(const short8*)(vb + coff);
    float pw = __expf(s[j] - M);
    lrun += pw;
#pragma unroll
    for (int d = 0; d < 8; d++) oa[d] += pw * bs2f(v8[d]);
  }
  float inv = 1.0f / lrun;
#pragma unroll
  for (int d = 0; d < 8; d++) oT[pp * 65 + head * 8 + d] = oa[d] * inv;
  __syncthreads();

  // output projection: wave wid -> channels wid*8..wid*8+7, lane l = position
  int wid = __builtin_amdgcn_readfirstlane(tid >> 6);
  int l = tid & 63;
  float acc[8];
#pragma unroll
  for (int u = 0; u < 8; u++) acc[u] = bo[wid * 8 + u];
  for (int j = 0; j < 64; j++) {
    float ov = oT[l * 65 + j];
    const float* wr = Wo + j * 64 + wid * 8;  // uniform -> s_load
#pragma unroll
    for (int u = 0; u < 8; u++) acc[u] += ov * wr[u];
  }
#pragma unroll
  for (int u = 0; u < 8; u++)
    out[(size_t)(wid * 8 + u) * NPOS + p0 + l] = acc[u];
}

extern "C" void kernel_launch(void* const* d_in, const int* in_sizes, int n_in,
                              void* d_out, int out_size, void* d_ws, size_t ws_size,
                              hipStream_t stream) {
  const float* x    = (const float*)d_in[0];
  const float* skip = (const float*)d_in[1];
  const float* Wq   = (const float*)d_in[2];
  const float* bq   = (const float*)d_in[3];
  const float* Wk   = (const float*)d_in[4];
  const float* bk   = (const float*)d_in[5];
  const float* Wv   = (const float*)d_in[6];
  const float* bv   = (const float*)d_in[7];
  const float* Wo   = (const float*)d_in[8];
  const float* bo   = (const float*)d_in[9];
  const float* rpb  = (const float*)d_in[10];

  // ws layout (32 MB + ~18 KB):
  bf16* xu        = (bf16*)d_ws;                                 // 8 MB
  bf16* kbuf      = (bf16*)((char*)d_ws + ((size_t)8 << 20));    // 8 MB
  bf16* vbuf      = (bf16*)((char*)d_ws + ((size_t)16 << 20));   // 8 MB
  bf16* qbuf      = (bf16*)((char*)d_ws + ((size_t)24 << 20));   // 8 MB
  float* stats    = (float*)((char*)d_ws + ((size_t)32 << 20));  // 256 fp32
  float* partials = stats + 256;                                 // 4096 fp32
  float* out = (float*)d_out;

  hipLaunchKernelGGL(k_partial, dim3(2048), dim3(256), 0, stream, x, skip, xu,
                     partials);
  hipLaunchKernelGGL(k_finalize, dim3(1), dim3(128), 0, stream, partials, stats);
  hipLaunchKernelGGL(k_proj_kvq, dim3(1024), dim3(256), 0, stream, xu, skip,
                     stats, Wk, bk, Wv, bv, Wq, bq, kbuf, vbuf, qbuf);
  hipLaunchKernelGGL(k_attn, dim3(1024), dim3(512), 0, stream, qbuf, kbuf, vbuf,
                     Wo, bo, rpb, out);
}

// Round 11
// 147.524 us; speedup vs baseline: 1.8027x; 1.0822x over previous
//
#include <hip/hip_runtime.h>
#include <hip/hip_bf16.h>

typedef __hip_bfloat16 bf16;
typedef __attribute__((ext_vector_type(8))) short short8;
typedef __attribute__((ext_vector_type(4))) float f32x4;

static constexpr int NPOS = 65536;  // 64*64*16

__device__ __forceinline__ float bs2f(short s) {
  union { float f; unsigned u; } cv;
  cv.u = ((unsigned)(unsigned short)s) << 16;
  return cv.f;
}
__device__ __forceinline__ short f2bs(float f) {
  bf16 b = __float2bfloat16(f);
  short r;
  __builtin_memcpy(&r, &b, 2);
  return r;
}

// K1a: partial sums + xu materialization (bf16). 2048 blocks. (unchanged)
__global__ __launch_bounds__(256) void k_partial(const float* __restrict__ x,
                                                 const float* __restrict__ skip,
                                                 bf16* __restrict__ xu,
                                                 float* __restrict__ partials) {
  __shared__ float s1[256];
  __shared__ float s2[256];
  int b = blockIdx.x, tid = threadIdx.x;
  float sum = 0.f, sq = 0.f;
  if (b < 1024) {
    int c = b >> 4;
    int h = (b & 15) * 4 + (tid >> 6);
    int w = tid & 63;
    float fh = (float)h * (31.0f / 63.0f);
    int ih = (int)fh; if (ih > 30) ih = 30;
    float wh = fh - (float)ih;
    float fw = (float)w * (31.0f / 63.0f);
    int iw = (int)fw; if (iw > 30) iw = 30;
    float ww = fw - (float)iw;
    const float* base = x + c * 8192 + ih * 256 + iw * 8;
    float4 A0 = *(const float4*)(base);
    float4 A1 = *(const float4*)(base + 4);
    float4 B0 = *(const float4*)(base + 8);
    float4 B1 = *(const float4*)(base + 12);
    float4 C0 = *(const float4*)(base + 256);
    float4 C1 = *(const float4*)(base + 260);
    float4 D0 = *(const float4*)(base + 264);
    float4 D1 = *(const float4*)(base + 268);
    float ra[8] = {A0.x, A0.y, A0.z, A0.w, A1.x, A1.y, A1.z, A1.w};
    float rb[8] = {B0.x, B0.y, B0.z, B0.w, B1.x, B1.y, B1.z, B1.w};
    float rc[8] = {C0.x, C0.y, C0.z, C0.w, C1.x, C1.y, C1.z, C1.w};
    float rd[8] = {D0.x, D0.y, D0.z, D0.w, D1.x, D1.y, D1.z, D1.w};
    short8 o0, o1;
#pragma unroll
    for (int z = 0; z < 16; z++) {
      float fz = (float)z * (7.0f / 15.0f);
      int iz = (int)fz; if (iz > 6) iz = 6;
      float wz = fz - (float)iz;
      float va = ra[iz] * (1.f - wz) + ra[iz + 1] * wz;
      float vb = rb[iz] * (1.f - wz) + rb[iz + 1] * wz;
      float vc = rc[iz] * (1.f - wz) + rc[iz + 1] * wz;
      float vd = rd[iz] * (1.f - wz) + rd[iz + 1] * wz;
      float v0 = va * (1.f - ww) + vb * ww;
      float v1 = vc * (1.f - ww) + vd * ww;
      float v = v0 * (1.f - wh) + v1 * wh;
      sum += v; sq += v * v;
      if (z < 8) o0[z] = f2bs(v); else o1[z - 8] = f2bs(v);
    }
    bf16* xo = xu + (size_t)c * NPOS + h * 1024 + w * 16;
    *(short8*)xo = o0;
    *(short8*)(xo + 8) = o1;
  } else {
    int bb = b - 1024;
    const float4* p =
        (const float4*)(skip + (size_t)(bb >> 4) * NPOS + (bb & 15) * 4096);
    for (int i = tid; i < 1024; i += 256) {
      float4 v = p[i];
      sum += v.x + v.y + v.z + v.w;
      sq += v.x * v.x + v.y * v.y + v.z * v.z + v.w * v.w;
    }
  }
  s1[tid] = sum; s2[tid] = sq;
  __syncthreads();
  for (int s = 128; s > 0; s >>= 1) {
    if (tid < s) { s1[tid] += s1[tid + s]; s2[tid] += s2[tid + s]; }
    __syncthreads();
  }
  if (tid == 0) { partials[2 * b] = s1[0]; partials[2 * b + 1] = s2[0]; }
}

// K2: MFMA projection. Per block: 64-pos tile; D = Xnorm·W + b for W in
// {Wk, Wv, Wq}. A/B staged in LDS as bf16 with pad-72 strides; stats folded
// in (redundant 16 KB partials reduction per block). Layouts per verified
// gfx950 mapping: A[m=lane&15][k=quad*8+i], B[n=lane&15][k=quad*8+i],
// D row=quad*4+reg, col=lane&15.
__global__ __launch_bounds__(256) void k_proj_mfma(
    const bf16* __restrict__ xu, const float* __restrict__ skip,
    const float* __restrict__ partials,
    const float* __restrict__ Wk, const float* __restrict__ bk,
    const float* __restrict__ Wv, const float* __restrict__ bv,
    const float* __restrict__ Wq, const float* __restrict__ bq,
    bf16* __restrict__ kbuf, bf16* __restrict__ vbuf, bf16* __restrict__ qbuf) {
  __shared__ float stl[256];     // [mean_xu, rstd_xu, mean_sk, rstd_sk] x64
  __shared__ short xa[64 * 72];  // A: [m=pos][k=c]
  __shared__ short wb[64 * 72];  // B: [n=j][k=c]  (W transposed)
  __shared__ short ob[64 * 72];  // D: [m][n]
  int tid = threadIdx.x;
  int p0 = blockIdx.x * 64;

  // fold finalize: stats from partials (L2-hot)
  if (tid < 128) {
    int isk = tid >> 6, c = tid & 63;
    int base = isk ? (1024 + c * 16) : (c * 16);
    float sum = 0.f, sq = 0.f;
#pragma unroll
    for (int j = 0; j < 16; j++) {
      sum += partials[2 * (base + j)];
      sq  += partials[2 * (base + j) + 1];
    }
    float m = sum * (1.0f / NPOS);
    float var = sq * (1.0f / NPOS) - m * m;
    stl[isk * 128 + c] = m;
    stl[isk * 128 + 64 + c] = rsqrtf(var + 1e-5f);
  }
  __syncthreads();

  // stage A from xu (normalized, transposed to [pos][c])
  for (int ii = tid; ii < 512; ii += 256) {
    int c = ii >> 3, t0 = (ii & 7) * 8;
    short8 v8 = *(const short8*)(xu + (size_t)c * NPOS + p0 + t0);
    float m = stl[c], r = stl[64 + c];
#pragma unroll
    for (int u = 0; u < 8; u++) xa[(t0 + u) * 72 + c] = f2bs((bs2f(v8[u]) - m) * r);
  }
  // stage B from Wk (bf16, transposed to [j][c])
  {
    int c = tid >> 2, j0 = (tid & 3) * 16;
    const float4* wr = (const float4*)(Wk + c * 64 + j0);
    float4 w0 = wr[0], w1 = wr[1], w2 = wr[2], w3 = wr[3];
    float wv[16] = {w0.x,w0.y,w0.z,w0.w, w1.x,w1.y,w1.z,w1.w,
                    w2.x,w2.y,w2.z,w2.w, w3.x,w3.y,w3.z,w3.w};
#pragma unroll
    for (int u = 0; u < 16; u++) wb[(j0 + u) * 72 + c] = f2bs(wv[u]);
  }
  __syncthreads();

  int wv_ = tid >> 6, lane = tid & 63, quad = lane >> 4, l15 = lane & 15;
  const short* arow = &xa[(wv_ * 16 + l15) * 72 + quad * 8];
  int orow0 = (wv_ * 16 + quad * 4);

  // ---- weight K ----
  {
    short8 a0 = *(const short8*)(arow);
    short8 a1 = *(const short8*)(arow + 32);
#pragma unroll
    for (int nt = 0; nt < 4; nt++) {
      const short* brow = &wb[(nt * 16 + l15) * 72 + quad * 8];
      short8 b0 = *(const short8*)(brow);
      short8 b1 = *(const short8*)(brow + 32);
      f32x4 acc = {0.f, 0.f, 0.f, 0.f};
      acc = __builtin_amdgcn_mfma_f32_16x16x32_bf16(a0, b0, acc, 0, 0, 0);
      acc = __builtin_amdgcn_mfma_f32_16x16x32_bf16(a1, b1, acc, 0, 0, 0);
      float bval = bk[nt * 16 + l15];
#pragma unroll
      for (int r = 0; r < 4; r++)
        ob[(orow0 + r) * 72 + nt * 16 + l15] = f2bs(acc[r] + bval);
    }
  }
  __syncthreads();
  // store K tile + restage B with Wv
  {
    int row = tid >> 2, col0 = (tid & 3) * 16;
    short8 o0 = *(const short8*)(&ob[row * 72 + col0]);
    short8 o1 = *(const short8*)(&ob[row * 72 + col0 + 8]);
    *(short8*)(kbuf + (size_t)(p0 + row) * 64 + col0) = o0;
    *(short8*)(kbuf + (size_t)(p0 + row) * 64 + col0 + 8) = o1;
    int c = tid >> 2, j0 = (tid & 3) * 16;
    const float4* wr = (const float4*)(Wv + c * 64 + j0);
    float4 w0 = wr[0], w1 = wr[1], w2 = wr[2], w3 = wr[3];
    float wvv[16] = {w0.x,w0.y,w0.z,w0.w, w1.x,w1.y,w1.z,w1.w,
                     w2.x,w2.y,w2.z,w2.w, w3.x,w3.y,w3.z,w3.w};
#pragma unroll
    for (int u = 0; u < 16; u++) wb[(j0 + u) * 72 + c] = f2bs(wvv[u]);
  }
  __syncthreads();
  // ---- weight V ----
  {
    short8 a0 = *(const short8*)(arow);
    short8 a1 = *(const short8*)(arow + 32);
#pragma unroll
    for (int nt = 0; nt < 4; nt++) {
      const short* brow = &wb[(nt * 16 + l15) * 72 + quad * 8];
      short8 b0 = *(const short8*)(brow);
      short8 b1 = *(const short8*)(brow + 32);
      f32x4 acc = {0.f, 0.f, 0.f, 0.f};
      acc = __builtin_amdgcn_mfma_f32_16x16x32_bf16(a0, b0, acc, 0, 0, 0);
      acc = __builtin_amdgcn_mfma_f32_16x16x32_bf16(a1, b1, acc, 0, 0, 0);
      float bval = bv[nt * 16 + l15];
#pragma unroll
      for (int r = 0; r < 4; r++)
        ob[(orow0 + r) * 72 + nt * 16 + l15] = f2bs(acc[r] + bval);
    }
  }
  __syncthreads();
  // store V tile + restage A from skip + restage B with Wq
  {
    int row = tid >> 2, col0 = (tid & 3) * 16;
    short8 o0 = *(const short8*)(&ob[row * 72 + col0]);
    short8 o1 = *(const short8*)(&ob[row * 72 + col0 + 8]);
    *(short8*)(vbuf + (size_t)(p0 + row) * 64 + col0) = o0;
    *(short8*)(vbuf + (size_t)(p0 + row) * 64 + col0 + 8) = o1;
  }
  for (int ii = tid; ii < 1024; ii += 256) {
    int c = ii >> 4, t0 = (ii & 15) * 4;
    float4 v = *(const float4*)(skip + (size_t)c * NPOS + p0 + t0);
    float m = stl[128 + c], r = stl[192 + c];
    xa[(t0 + 0) * 72 + c] = f2bs((v.x - m) * r);
    xa[(t0 + 1) * 72 + c] = f2bs((v.y - m) * r);
    xa[(t0 + 2) * 72 + c] = f2bs((v.z - m) * r);
    xa[(t0 + 3) * 72 + c] = f2bs((v.w - m) * r);
  }
  {
    int c = tid >> 2, j0 = (tid & 3) * 16;
    const float4* wr = (const float4*)(Wq + c * 64 + j0);
    float4 w0 = wr[0], w1 = wr[1], w2 = wr[2], w3 = wr[3];
    float wq_[16] = {w0.x,w0.y,w0.z,w0.w, w1.x,w1.y,w1.z,w1.w,
                     w2.x,w2.y,w2.z,w2.w, w3.x,w3.y,w3.z,w3.w};
#pragma unroll
    for (int u = 0; u < 16; u++) wb[(j0 + u) * 72 + c] = f2bs(wq_[u]);
  }
  __syncthreads();
  // ---- weight Q (pre-scaled by 8^-0.5) ----
  {
    const float scale = 0.35355339059327373f;
    short8 a0 = *(const short8*)(arow);
    short8 a1 = *(const short8*)(arow + 32);
#pragma unroll
    for (int nt = 0; nt < 4; nt++) {
      const short* brow = &wb[(nt * 16 + l15) * 72 + quad * 8];
      short8 b0 = *(const short8*)(brow);
      short8 b1 = *(const short8*)(brow + 32);
      f32x4 acc = {0.f, 0.f, 0.f, 0.f};
      acc = __builtin_amdgcn_mfma_f32_16x16x32_bf16(a0, b0, acc, 0, 0, 0);
      acc = __builtin_amdgcn_mfma_f32_16x16x32_bf16(a1, b1, acc, 0, 0, 0);
      float bval = bq[nt * 16 + l15];
#pragma unroll
      for (int r = 0; r < 4; r++)
        ob[(orow0 + r) * 72 + nt * 16 + l15] = f2bs((acc[r] + bval) * scale);
    }
  }
  __syncthreads();
  {
    int row = tid >> 2, col0 = (tid & 3) * 16;
    short8 o0 = *(const short8*)(&ob[row * 72 + col0]);
    short8 o1 = *(const short8*)(&ob[row * 72 + col0 + 8]);
    *(short8*)(qbuf + (size_t)(p0 + row) * 64 + col0) = o0;
    *(short8*)(qbuf + (size_t)(p0 + row) * 64 + col0 + 8) = o1;
  }
}

// K3: 27-neighbor attention, flat softmax. (unchanged from R10: 46 µs)
__global__ __launch_bounds__(512, 2) void k_attn(
    const bf16* __restrict__ qbuf, const bf16* __restrict__ kbuf,
    const bf16* __restrict__ vbuf,
    const float* __restrict__ Wo, const float* __restrict__ bo,
    const float* __restrict__ rpb, float* __restrict__ out) {
  __shared__ float rp[1000];
  __shared__ float oT[64 * 65];
  int tid = threadIdx.x;
  int b = blockIdx.x;
  int sb = ((b & 7) << 7) + (b >> 3);
  int p0 = sb * 64;
  for (int i = tid; i < 1000; i += 512) rp[i] = rpb[i];
  __syncthreads();

  int head = tid & 7, pp = tid >> 3;
  int p = p0 + pp;
  int h = p >> 10, w = (p >> 4) & 63, z = p & 15;

  short8 q8 = *(const short8*)(qbuf + (size_t)p * 64 + head * 8);
  float q[8];
#pragma unroll
  for (int d = 0; d < 8; d++) q[d] = bs2f(q8[d]);

  int sh = h - 1; if (sh < 0) sh = 0; if (sh > 61) sh = 61;
  int sw = w - 1; if (sw < 0) sw = 0; if (sw > 61) sw = 61;
  int sz = z - 1; if (sz < 0) sz = 0; if (sz > 13) sz = 13;

  const bf16* kb = kbuf + (size_t)(sh * 1024 + sw * 16 + sz) * 64 + head * 8;
  const bf16* vb = vbuf + (size_t)(sh * 1024 + sw * 16 + sz) * 64 + head * 8;
  int rbase = ((sh - h + 2) * 5 + (sw - w + 2)) * 5 + (sz - z + 2) + head * 125;

  float s[27];
#pragma unroll
  for (int j = 0; j < 27; j++) {
    int kh = j / 9, kw = (j % 9) / 3, kz = j % 3;
    int coff = (kh * 1024 + kw * 16 + kz) * 64;
    short8 k8 = *(const short8*)(kb + coff);
    float sv = q[0] * bs2f(k8[0]) + q[1] * bs2f(k8[1]) +
               q[2] * bs2f(k8[2]) + q[3] * bs2f(k8[3]) +
               q[4] * bs2f(k8[4]) + q[5] * bs2f(k8[5]) +
               q[6] * bs2f(k8[6]) + q[7] * bs2f(k8[7]);
    s[j] = sv + rp[rbase + (kh * 5 + kw) * 5 + kz];
  }
  float M = s[26];
#pragma unroll
  for (int j = 0; j < 13; j++) M = fmaxf(M, fmaxf(s[2 * j], s[2 * j + 1]));

  float lrun = 0.f;
  float oa[8];
#pragma unroll
  for (int d = 0; d < 8; d++) oa[d] = 0.f;
#pragma unroll
  for (int j = 0; j < 27; j++) {
    int kh = j / 9, kw = (j % 9) / 3, kz = j % 3;
    int coff = (kh * 1024 + kw * 16 + kz) * 64;
    short8 v8 = *(const short8*)(vb + coff);
    float pw = __expf(s[j] - M);
    lrun += pw;
#pragma unroll
    for (int d = 0; d < 8; d++) oa[d] += pw * bs2f(v8[d]);
  }
  float inv = 1.0f / lrun;
#pragma unroll
  for (int d = 0; d < 8; d++) oT[pp * 65 + head * 8 + d] = oa[d] * inv;
  __syncthreads();

  int wid = __builtin_amdgcn_readfirstlane(tid >> 6);
  int l = tid & 63;
  float acc[8];
#pragma unroll
  for (int u = 0; u < 8; u++) acc[u] = bo[wid * 8 + u];
  for (int j = 0; j < 64; j++) {
    float ov = oT[l * 65 + j];
    const float* wr = Wo + j * 64 + wid * 8;
#pragma unroll
    for (int u = 0; u < 8; u++) acc[u] += ov * wr[u];
  }
#pragma unroll
  for (int u = 0; u < 8; u++)
    out[(size_t)(wid * 8 + u) * NPOS + p0 + l] = acc[u];
}

extern "C" void kernel_launch(void* const* d_in, const int* in_sizes, int n_in,
                              void* d_out, int out_size, void* d_ws, size_t ws_size,
                              hipStream_t stream) {
  const float* x    = (const float*)d_in[0];
  const float* skip = (const float*)d_in[1];
  const float* Wq   = (const float*)d_in[2];
  const float* bq   = (const float*)d_in[3];
  const float* Wk   = (const float*)d_in[4];
  const float* bk   = (const float*)d_in[5];
  const float* Wv   = (const float*)d_in[6];
  const float* bv   = (const float*)d_in[7];
  const float* Wo   = (const float*)d_in[8];
  const float* bo   = (const float*)d_in[9];
  const float* rpb  = (const float*)d_in[10];

  // ws layout (32 MB + ~18 KB):
  bf16* xu        = (bf16*)d_ws;                                 // 8 MB
  bf16* kbuf      = (bf16*)((char*)d_ws + ((size_t)8 << 20));    // 8 MB
  bf16* vbuf      = (bf16*)((char*)d_ws + ((size_t)16 << 20));   // 8 MB
  bf16* qbuf      = (bf16*)((char*)d_ws + ((size_t)24 << 20));   // 8 MB
  float* partials = (float*)((char*)d_ws + ((size_t)32 << 20));  // 4096 fp32
  float* out = (float*)d_out;

  hipLaunchKernelGGL(k_partial, dim3(2048), dim3(256), 0, stream, x, skip, xu,
                     partials);
  hipLaunchKernelGGL(k_proj_mfma, dim3(1024), dim3(256), 0, stream, xu, skip,
                     partials, Wk, bk, Wv, bv, Wq, bq, kbuf, vbuf, qbuf);
  hipLaunchKernelGGL(k_attn, dim3(1024), dim3(512), 0, stream, qbuf, kbuf, vbuf,
                     Wo, bo, rpb, out);
}